// Round 1
// baseline (102.764 us; speedup 1.0000x reference)
//
#include <hip/hip_runtime.h>
#include <hip/hip_bf16.h>
#include <cstdint>
#include <cstddef>

typedef __attribute__((ext_vector_type(8))) short short8;   // 8 x bf16 bits (4 VGPRs)
typedef __attribute__((ext_vector_type(4))) float f32x4;

#define BLOCK 256
#define GRID  1024

// One wave handles one batch at a time.
// Lane l: n = l&15 (member index / score column), g = l>>4 (k-group).
// H rows: lane computes H[n][h] for h in {32s + 8g + j}, s=0..3, j=0..7 —
// exactly the A-frag (and identical B-frag) for mfma_f32_16x16x32_bf16 Gram.
__global__ __launch_bounds__(BLOCK) void postpro_kernel(
    const float* __restrict__ prob,
    const float* __restrict__ W1,
    const float* __restrict__ b1,
    const float* __restrict__ W2,
    const float* __restrict__ b2,
    float* __restrict__ out,
    int nBatch, int batchesPerWave)
{
    __shared__ float sW1[3 * 128];     // W1 rows 0..2 (prob features), row-major [d][h]
    __shared__ float sW2T[3 * 128];    // W2 transposed: [c][h]
    __shared__ float sBase[16 * 132];  // b1[h] + m*W1[3][h], padded stride 132

    const int tid = threadIdx.x;
    for (int i = tid; i < 384; i += BLOCK) sW1[i] = W1[i];
    for (int i = tid; i < 384; i += BLOCK) {
        int c = i >> 7, h = i & 127;
        sW2T[i] = W2[h * 3 + c];
    }
    for (int i = tid; i < 2048; i += BLOCK) {
        int m = i >> 7, h = i & 127;
        sBase[m * 132 + h] = b1[h] + (float)m * W1[3 * 128 + h];
    }
    __syncthreads();

    const float bb2_0 = b2[0], bb2_1 = b2[1], bb2_2 = b2[2];

    const int lane = tid & 63;
    const int n    = lane & 15;
    const int g    = lane >> 4;
    const int wave = blockIdx.x * (BLOCK / 64) + (tid >> 6);
    const int b0   = wave * batchesPerWave;

    #pragma unroll 1
    for (int bi = 0; bi < batchesPerWave; ++bi) {
        const int b = b0 + bi;
        if (b >= nBatch) break;

        // x[n] = (p0, p1, p2, n); the n*W1[3] + b1 part is prebaked into sBase.
        const float* pb = prob + (size_t)b * 48 + n * 3;
        const float p0 = pb[0], p1 = pb[1], p2 = pb[2];

        short8 Ahi[4], Alo[4];
        float Y0 = 0.f, Y1 = 0.f, Y2 = 0.f;   // partial Y[n][c] over this lane's h-set

        #pragma unroll
        for (int s = 0; s < 4; ++s) {
            const int h0 = s * 32 + g * 8;
            float H[8];
            {
                const float* bs = &sBase[n * 132 + h0];
                #pragma unroll
                for (int j = 0; j < 8; ++j) H[j] = bs[j];
            }
            {
                const float* ws = &sW1[h0];
                #pragma unroll
                for (int j = 0; j < 8; ++j) H[j] = fmaf(p0, ws[j], H[j]);
            }
            {
                const float* ws = &sW1[128 + h0];
                #pragma unroll
                for (int j = 0; j < 8; ++j) H[j] = fmaf(p1, ws[j], H[j]);
            }
            {
                const float* ws = &sW1[256 + h0];
                #pragma unroll
                for (int j = 0; j < 8; ++j) H[j] = fmaf(p2, ws[j], H[j]);
            }
            #pragma unroll
            for (int j = 0; j < 8; ++j) H[j] = fmaxf(H[j], 0.0f);

            // Y partials (uses relu'd H)
            {
                const float* w0 = &sW2T[h0];
                const float* w1 = &sW2T[128 + h0];
                const float* w2 = &sW2T[256 + h0];
                #pragma unroll
                for (int j = 0; j < 8; ++j) {
                    Y0 = fmaf(H[j], w0[j], Y0);
                    Y1 = fmaf(H[j], w1[j], Y1);
                    Y2 = fmaf(H[j], w2[j], Y2);
                }
            }

            // hi/lo bf16 truncation split: H = hi + lo exactly to ~2^-17 rel
            uint32_t hiU[8], loU[8];
            #pragma unroll
            for (int j = 0; j < 8; ++j) {
                uint32_t u  = __float_as_uint(H[j]);
                uint32_t hm = u & 0xFFFF0000u;
                hiU[j] = hm;
                loU[j] = __float_as_uint(H[j] - __uint_as_float(hm));
            }
            union { short8 v; uint32_t u[4]; } fh, fl;
            #pragma unroll
            for (int k = 0; k < 4; ++k) {
                fh.u[k] = (hiU[2 * k] >> 16) | hiU[2 * k + 1];                  // hiU already masked
                fl.u[k] = (loU[2 * k] >> 16) | (loU[2 * k + 1] & 0xFFFF0000u);
            }
            Ahi[s] = fh.v;
            Alo[s] = fl.v;
        }

        // scores = Hhi·Hhi^T + Hhi·Hlo^T + Hlo·Hhi^T   (lo·lo negligible)
        f32x4 acc = {0.f, 0.f, 0.f, 0.f};
        #pragma unroll
        for (int s = 0; s < 4; ++s) {
            acc = __builtin_amdgcn_mfma_f32_16x16x32_bf16(Ahi[s], Ahi[s], acc, 0, 0, 0);
            acc = __builtin_amdgcn_mfma_f32_16x16x32_bf16(Ahi[s], Alo[s], acc, 0, 0, 0);
            acc = __builtin_amdgcn_mfma_f32_16x16x32_bf16(Alo[s], Ahi[s], acc, 0, 0, 0);
        }

        // softmax over cols: C layout => lane holds scores[4g+r][n], r=0..3
        float attnw[4];
        #pragma unroll
        for (int r = 0; r < 4; ++r) {
            float v = acc[r];
            float mx = v;
            #pragma unroll
            for (int msk = 1; msk <= 8; msk <<= 1)
                mx = fmaxf(mx, __shfl_xor(mx, msk));
            float e = __expf(v - mx);
            float sm = e;
            #pragma unroll
            for (int msk = 1; msk <= 8; msk <<= 1)
                sm += __shfl_xor(sm, msk);
            attnw[r] = e / sm;
        }

        // full Y[n][c]: reduce partials over the 4 g-groups (lanes n, n+16, n+32, n+48)
        Y0 += __shfl_xor(Y0, 16); Y0 += __shfl_xor(Y0, 32);
        Y1 += __shfl_xor(Y1, 16); Y1 += __shfl_xor(Y1, 32);
        Y2 += __shfl_xor(Y2, 16); Y2 += __shfl_xor(Y2, 32);

        // out[4g+r][c] = sum_n attn[4g+r][n] * Y[n][c] + b2[c]
        float o[12];
        #pragma unroll
        for (int r = 0; r < 4; ++r) {
            o[r * 3 + 0] = attnw[r] * Y0;
            o[r * 3 + 1] = attnw[r] * Y1;
            o[r * 3 + 2] = attnw[r] * Y2;
        }
        #pragma unroll
        for (int msk = 1; msk <= 8; msk <<= 1) {
            #pragma unroll
            for (int i = 0; i < 12; ++i) o[i] += __shfl_xor(o[i], msk);
        }
        o[0] += bb2_0; o[1] += bb2_1; o[2]  += bb2_2;
        o[3] += bb2_0; o[4] += bb2_1; o[5]  += bb2_2;
        o[6] += bb2_0; o[7] += bb2_1; o[8]  += bb2_2;
        o[9] += bb2_0; o[10] += bb2_1; o[11] += bb2_2;

        // group g owns rows 4g..4g+3 -> flat f32 offsets b*48 + 12g + [0..11]
        if (n == 0) {
            float* dst = out + (size_t)b * 48 + g * 12;
            f32x4 q0 = {o[0], o[1], o[2],  o[3]};
            f32x4 q1 = {o[4], o[5], o[6],  o[7]};
            f32x4 q2 = {o[8], o[9], o[10], o[11]};
            *(f32x4*)(dst + 0) = q0;
            *(f32x4*)(dst + 4) = q1;
            *(f32x4*)(dst + 8) = q2;
        }
    }
}

extern "C" void kernel_launch(void* const* d_in, const int* in_sizes, int n_in,
                              void* d_out, int out_size, void* d_ws, size_t ws_size,
                              hipStream_t stream) {
    const float* prob = (const float*)d_in[0];
    const float* W1   = (const float*)d_in[1];
    const float* b1   = (const float*)d_in[2];
    const float* W2   = (const float*)d_in[3];
    const float* b2   = (const float*)d_in[4];
    float* out        = (float*)d_out;

    const int nBatch = in_sizes[0] / 48;                // [B,16,3]
    const int totalWaves = GRID * (BLOCK / 64);
    const int bpw = (nBatch + totalWaves - 1) / totalWaves;

    postpro_kernel<<<GRID, BLOCK, 0, stream>>>(prob, W1, b1, W2, b2, out, nBatch, bpw);
}

// Round 3
// 57.540 us; speedup vs baseline: 1.7860x; 1.7860x over previous
//
#include <hip/hip_runtime.h>
#include <cstdint>
#include <cstddef>

typedef __attribute__((ext_vector_type(8))) short short8;   // 8 x bf16 bits
typedef __attribute__((ext_vector_type(4))) float f32x4;

#define BLOCK 256
#define GRID  2048
#define NB    4

// round-half-up bf16, returned as masked-high-bits uint
__device__ __forceinline__ uint32_t bf16_rnd_hi(float x) {
    return (__float_as_uint(x) + 0x8000u) & 0xFFFF0000u;
}

// Lane l: p16 = l&15, g = l>>4. Logical element->feature convention used for
// EVERY MFMA operand in this kernel: element j of chunk s <-> k = 32s + 8g + j.
// Round 1's Gram pass proves the HW A/B lane->k maps are row-independent
// mirrors, so this convention cancels on both sides of every product.
__global__ __launch_bounds__(BLOCK, 2) void postpro_kernel(
    const float* __restrict__ prob,
    const float* __restrict__ W1,
    const float* __restrict__ b1,
    const float* __restrict__ W2,
    const float* __restrict__ b2,
    float* __restrict__ out,
    int nBatch, int bpw)
{
    __shared__ float sw[640];   // [0:512) W1 rows 0..3, [512:640) b1
    const int tid = threadIdx.x;
    for (int i = tid; i < 512; i += BLOCK) sw[i] = W1[i];
    for (int i = tid; i < 128; i += BLOCK) sw[512 + i] = b1[i];
    __syncthreads();

    const int lane = tid & 63;
    const int p16  = lane & 15;
    const int g    = lane >> 4;
    const float fn = (float)p16;

    // W2 B-frags: element j of chunk s = W2[32s+8g+j][c=p16] (bf16 rne-ish)
    short8 w2f[4];
    #pragma unroll
    for (int s = 0; s < 4; ++s) {
        union { short8 v; uint32_t q[4]; } pk;
        #pragma unroll
        for (int t = 0; t < 4; ++t) {
            const int k0 = 32 * s + 8 * g + 2 * t;
            const uint32_t u0 = (p16 < 3) ? bf16_rnd_hi(W2[k0 * 3 + p16]) : 0u;
            const uint32_t u1 = (p16 < 3) ? bf16_rnd_hi(W2[(k0 + 1) * 3 + p16]) : 0u;
            pk.q[t] = (u0 >> 16) | u1;
        }
        w2f[s] = pk.v;
    }
    const float binit = (p16 < 3) ? b2[p16] : 0.0f;   // b2 fold: sum(attn)=1
    const f32x4 yinit = {binit, binit, binit, binit};
    const f32x4 zero4 = {0.f, 0.f, 0.f, 0.f};

    const int wave = blockIdx.x * (BLOCK / 64) + (tid >> 6);
    const int b0   = wave * bpw;

    for (int bi = 0; bi < bpw; bi += NB) {
        const int bb = b0 + bi;

        float p0[NB], p1[NB], p2[NB];
        #pragma unroll
        for (int u = 0; u < NB; ++u) {
            int b = bb + u; if (b > nBatch - 1) b = nBatch - 1;
            const float* pp = prob + (size_t)b * 48 + p16 * 3;
            p0[u] = pp[0]; p1[u] = pp[1]; p2[u] = pp[2];
        }

        f32x4 accS[NB], accY[NB];
        #pragma unroll
        for (int u = 0; u < NB; ++u) { accS[u] = zero4; accY[u] = yinit; }

        #pragma unroll
        for (int s = 0; s < 4; ++s) {
            const int h0 = 32 * s + 8 * g;
            const f32x4 r0a = *(const f32x4*)(sw + h0);
            const f32x4 r0b = *(const f32x4*)(sw + h0 + 4);
            const f32x4 r1a = *(const f32x4*)(sw + 128 + h0);
            const f32x4 r1b = *(const f32x4*)(sw + 128 + h0 + 4);
            const f32x4 r2a = *(const f32x4*)(sw + 256 + h0);
            const f32x4 r2b = *(const f32x4*)(sw + 256 + h0 + 4);
            const f32x4 w3a = *(const f32x4*)(sw + 384 + h0);
            const f32x4 w3b = *(const f32x4*)(sw + 384 + h0 + 4);
            const f32x4 b1a = *(const f32x4*)(sw + 512 + h0);
            const f32x4 b1b = *(const f32x4*)(sw + 512 + h0 + 4);

            float r0_[8], r1_[8], r2_[8], base_[8];
            #pragma unroll
            for (int j = 0; j < 4; ++j) {
                r0_[j] = r0a[j]; r0_[4 + j] = r0b[j];
                r1_[j] = r1a[j]; r1_[4 + j] = r1b[j];
                r2_[j] = r2a[j]; r2_[4 + j] = r2b[j];
                base_[j]     = fmaf(fn, w3a[j], b1a[j]);
                base_[4 + j] = fmaf(fn, w3b[j], b1b[j]);
            }

            #pragma unroll
            for (int u = 0; u < NB; ++u) {
                float H[8];
                #pragma unroll
                for (int j = 0; j < 8; ++j) {
                    float h = fmaf(p0[u], r0_[j], base_[j]);
                    h = fmaf(p1[u], r1_[j], h);
                    h = fmaf(p2[u], r2_[j], h);
                    H[j] = fmaxf(h, 0.0f);
                }
                // truncation hi/lo split (round-1-verified bit ops, no asm)
                uint32_t hu[8]; float lo[8];
                #pragma unroll
                for (int j = 0; j < 8; ++j) {
                    hu[j] = __float_as_uint(H[j]) & 0xFFFF0000u;
                    lo[j] = H[j] - __uint_as_float(hu[j]);
                }
                union { short8 v; uint32_t q[4]; } Ah, Al;
                #pragma unroll
                for (int t = 0; t < 4; ++t) {
                    Ah.q[t] = (hu[2 * t] >> 16) | hu[2 * t + 1];
                    Al.q[t] = (__float_as_uint(lo[2 * t]) >> 16) |
                              (__float_as_uint(lo[2 * t + 1]) & 0xFFFF0000u);
                }
                accS[u] = __builtin_amdgcn_mfma_f32_16x16x32_bf16(Ah.v, Ah.v, accS[u], 0, 0, 0);
                accS[u] = __builtin_amdgcn_mfma_f32_16x16x32_bf16(Ah.v, Al.v, accS[u], 0, 0, 0);
                accS[u] = __builtin_amdgcn_mfma_f32_16x16x32_bf16(Al.v, Ah.v, accS[u], 0, 0, 0);
                accY[u] = __builtin_amdgcn_mfma_f32_16x16x32_bf16(Ah.v, w2f[s], accY[u], 0, 0, 0);
                accY[u] = __builtin_amdgcn_mfma_f32_16x16x32_bf16(Al.v, w2f[s], accY[u], 0, 0, 0);
            }
        }

        #pragma unroll
        for (int u = 0; u < NB; ++u) {
            const int b = bb + u;
            // transposed softmax: accS[u][r] = S[4g+r][p16] = S[p16][4g+r] (symmetric)
            float m0 = fmaxf(fmaxf(accS[u][0], accS[u][1]), fmaxf(accS[u][2], accS[u][3]));
            m0 = fmaxf(m0, __shfl_xor(m0, 16));
            m0 = fmaxf(m0, __shfl_xor(m0, 32));
            const float e0 = __expf(accS[u][0] - m0);
            const float e1 = __expf(accS[u][1] - m0);
            const float e2 = __expf(accS[u][2] - m0);
            const float e3 = __expf(accS[u][3] - m0);
            float sm = (e0 + e1) + (e2 + e3);
            sm += __shfl_xor(sm, 16);
            sm += __shfl_xor(sm, 32);
            const float inv = __builtin_amdgcn_rcpf(sm);
            const float aw[4] = {e0 * inv, e1 * inv, e2 * inv, e3 * inv};

            // epilogue on the SAME verified instruction:
            // A[c][k] (c=p16): slot j<4 -> hi(Y'[4g+j][c]), slot j>=4 -> lo(Y'[4g+j-4][c])
            // B[k][m] (m=p16): slot j<4 -> hi(attn[m][4g+j]), j>=4 -> lo(...)
            uint32_t yh[4], ah[4]; float yl[4], al[4];
            #pragma unroll
            for (int r = 0; r < 4; ++r) {
                const uint32_t uy = __float_as_uint(accY[u][r]) & 0xFFFF0000u;
                yh[r] = uy; yl[r] = accY[u][r] - __uint_as_float(uy);
                const uint32_t ua = __float_as_uint(aw[r]) & 0xFFFF0000u;
                ah[r] = ua; al[r] = aw[r] - __uint_as_float(ua);
            }
            union { short8 v; uint32_t q[4]; } Afr, Asw, Bfr;
            Afr.q[0] = (yh[0] >> 16) | yh[1];
            Afr.q[1] = (yh[2] >> 16) | yh[3];
            Afr.q[2] = (__float_as_uint(yl[0]) >> 16) | (__float_as_uint(yl[1]) & 0xFFFF0000u);
            Afr.q[3] = (__float_as_uint(yl[2]) >> 16) | (__float_as_uint(yl[3]) & 0xFFFF0000u);
            Bfr.q[0] = (ah[0] >> 16) | ah[1];
            Bfr.q[1] = (ah[2] >> 16) | ah[3];
            Bfr.q[2] = (__float_as_uint(al[0]) >> 16) | (__float_as_uint(al[1]) & 0xFFFF0000u);
            Bfr.q[3] = (__float_as_uint(al[2]) >> 16) | (__float_as_uint(al[3]) & 0xFFFF0000u);
            Asw.q[0] = Afr.q[2]; Asw.q[1] = Afr.q[3];   // half-swapped A: lo<->hi slots
            Asw.q[2] = Afr.q[0]; Asw.q[3] = Afr.q[1];

            f32x4 D = __builtin_amdgcn_mfma_f32_16x16x32_bf16(Afr.v, Bfr.v, zero4, 0, 0, 0);
            D = __builtin_amdgcn_mfma_f32_16x16x32_bf16(Asw.v, Bfr.v, D, 0, 0, 0);
            // D[c'=4g+r][m=p16]; classes live in g==0 regs 0..2

            if (g == 0 && b < nBatch) {
                float* dst = out + (size_t)b * 48 + p16 * 3;
                dst[0] = D[0]; dst[1] = D[1]; dst[2] = D[2];
            }
        }
    }
}

extern "C" void kernel_launch(void* const* d_in, const int* in_sizes, int n_in,
                              void* d_out, int out_size, void* d_ws, size_t ws_size,
                              hipStream_t stream) {
    const float* prob = (const float*)d_in[0];
    const float* W1   = (const float*)d_in[1];
    const float* b1   = (const float*)d_in[2];
    const float* W2   = (const float*)d_in[3];
    const float* b2   = (const float*)d_in[4];
    float* out        = (float*)d_out;

    const int nBatch = in_sizes[0] / 48;                    // [B,16,3]
    const int totalWaves = GRID * (BLOCK / 64);
    const int bpw = (nBatch + totalWaves - 1) / totalWaves; // 8 at B=65536

    postpro_kernel<<<GRID, BLOCK, 0, stream>>>(prob, W1, b1, W2, b2, out, nBatch, bpw);
}

// Round 5
// 45.375 us; speedup vs baseline: 2.2648x; 1.2681x over previous
//
#include <hip/hip_runtime.h>
#include <cstdint>
#include <cstddef>

typedef __attribute__((ext_vector_type(4))) float f32x4;
typedef _Float16 h16x8 __attribute__((ext_vector_type(8)));

#define BLOCK 256
#define GRID  2048
#define NB    4

__device__ __forceinline__ uint32_t pk16(float a, float b) {
    // lo half = cvt(a), hi half = cvt(b), round-toward-zero
    return __builtin_bit_cast(uint32_t, __builtin_amdgcn_cvt_pkrtz(a, b));
}

// Lane l: p16 = l&15, g = l>>4. Element->feature convention for every MFMA
// operand: element j of chunk s <-> k = 32s + 8g + j (round-3-verified mirror).
__global__ __launch_bounds__(BLOCK, 2) void postpro_kernel(
    const float* __restrict__ prob,
    const float* __restrict__ W1,
    const float* __restrict__ b1,
    const float* __restrict__ W2,
    const float* __restrict__ b2,
    float* __restrict__ out,
    int nBatch, int bpw)
{
    __shared__ float sw[640];   // [0:512) W1 rows 0..3, [512:640) b1
    const int tid = threadIdx.x;
    for (int i = tid; i < 512; i += BLOCK) sw[i] = W1[i];
    for (int i = tid; i < 128; i += BLOCK) sw[512 + i] = b1[i];
    __syncthreads();

    const int lane = tid & 63;
    const int p16  = lane & 15;
    const int g    = lane >> 4;
    const float fn = (float)p16;

    // W2 B-frags (fp16): element j of chunk s = W2[32s+8g+j][c=p16], 0 for c>=3
    h16x8 w2f[4];
    #pragma unroll
    for (int s = 0; s < 4; ++s) {
        union { h16x8 v; _Float16 h[8]; } pk;
        #pragma unroll
        for (int j = 0; j < 8; ++j) {
            const int k = 32 * s + 8 * g + j;
            pk.h[j] = (p16 < 3) ? (_Float16)W2[k * 3 + p16] : (_Float16)0.0f;
        }
        w2f[s] = pk.v;
    }
    const float binit = (p16 < 3) ? b2[p16] : 0.0f;   // b2 fold: sum(attn)=1
    const f32x4 yinit = {binit, binit, binit, binit};
    const f32x4 zero4 = {0.f, 0.f, 0.f, 0.f};

    const int wave = blockIdx.x * (BLOCK / 64) + (tid >> 6);
    const int b0   = wave * bpw;

    for (int bi = 0; bi < bpw; bi += NB) {
        const int bb = b0 + bi;

        float p0[NB], p1[NB], p2[NB];
        #pragma unroll
        for (int u = 0; u < NB; ++u) {
            int b = bb + u; if (b > nBatch - 1) b = nBatch - 1;
            const float* pp = prob + (size_t)b * 48 + p16 * 3;
            p0[u] = pp[0]; p1[u] = pp[1]; p2[u] = pp[2];
        }

        f32x4 accS[NB], accY[NB];
        #pragma unroll
        for (int u = 0; u < NB; ++u) { accS[u] = zero4; accY[u] = yinit; }

        #pragma unroll
        for (int s = 0; s < 4; ++s) {
            const int h0 = 32 * s + 8 * g;
            const f32x4 r0a = *(const f32x4*)(sw + h0);
            const f32x4 r0b = *(const f32x4*)(sw + h0 + 4);
            const f32x4 r1a = *(const f32x4*)(sw + 128 + h0);
            const f32x4 r1b = *(const f32x4*)(sw + 128 + h0 + 4);
            const f32x4 r2a = *(const f32x4*)(sw + 256 + h0);
            const f32x4 r2b = *(const f32x4*)(sw + 256 + h0 + 4);
            const f32x4 w3a = *(const f32x4*)(sw + 384 + h0);
            const f32x4 w3b = *(const f32x4*)(sw + 384 + h0 + 4);
            const f32x4 b1a = *(const f32x4*)(sw + 512 + h0);
            const f32x4 b1b = *(const f32x4*)(sw + 512 + h0 + 4);

            float r0_[8], r1_[8], r2_[8], base_[8];
            #pragma unroll
            for (int j = 0; j < 4; ++j) {
                r0_[j] = r0a[j]; r0_[4 + j] = r0b[j];
                r1_[j] = r1a[j]; r1_[4 + j] = r1b[j];
                r2_[j] = r2a[j]; r2_[4 + j] = r2b[j];
                base_[j]     = fmaf(fn, w3a[j], b1a[j]);   // batch-invariant
                base_[4 + j] = fmaf(fn, w3b[j], b1b[j]);
            }

            #pragma unroll
            for (int u = 0; u < NB; ++u) {
                float H[8];
                #pragma unroll
                for (int j = 0; j < 8; ++j) {
                    float h = fmaf(p0[u], r0_[j], base_[j]);
                    h = fmaf(p1[u], r1_[j], h);
                    h = fmaf(p2[u], r2_[j], h);
                    H[j] = fmaxf(h, 0.0f);
                }
                union { h16x8 v; uint32_t q[4]; } Hf;
                #pragma unroll
                for (int t = 0; t < 4; ++t) Hf.q[t] = pk16(H[2 * t], H[2 * t + 1]);

                accS[u] = __builtin_amdgcn_mfma_f32_16x16x32_f16(Hf.v, Hf.v,   accS[u], 0, 0, 0);
                accY[u] = __builtin_amdgcn_mfma_f32_16x16x32_f16(Hf.v, w2f[s], accY[u], 0, 0, 0);
            }
        }

        #pragma unroll
        for (int u = 0; u < NB; ++u) {
            const int b = bb + u;
            // transposed softmax: accS[u][r] = S[4g+r][p16] = S[p16][4g+r] (symmetric)
            float m0 = fmaxf(fmaxf(accS[u][0], accS[u][1]), fmaxf(accS[u][2], accS[u][3]));
            m0 = fmaxf(m0, __shfl_xor(m0, 16));
            m0 = fmaxf(m0, __shfl_xor(m0, 32));
            const float e0 = __expf(accS[u][0] - m0);
            const float e1 = __expf(accS[u][1] - m0);
            const float e2 = __expf(accS[u][2] - m0);
            const float e3 = __expf(accS[u][3] - m0);
            float sm = (e0 + e1) + (e2 + e3);
            sm += __shfl_xor(sm, 16);
            sm += __shfl_xor(sm, 32);
            const float inv = __builtin_amdgcn_rcpf(sm);

            // epilogue: D[c][m] = sum_k Y'^T[c][k] attn^T[k][m], K=16 logical.
            // A elem j<4 (phys k=8g+j) = Y'16[4g+j][c=p16]; j>=4 = 0. Same for B.
            union { h16x8 v; uint32_t q[4]; } Afr, Bfr;
            Afr.q[0] = pk16(accY[u][0], accY[u][1]);
            Afr.q[1] = pk16(accY[u][2], accY[u][3]);
            Afr.q[2] = 0u; Afr.q[3] = 0u;
            Bfr.q[0] = pk16(e0 * inv, e1 * inv);
            Bfr.q[1] = pk16(e2 * inv, e3 * inv);
            Bfr.q[2] = 0u; Bfr.q[3] = 0u;

            const f32x4 D = __builtin_amdgcn_mfma_f32_16x16x32_f16(Afr.v, Bfr.v, zero4, 0, 0, 0);
            // D reg r, lane p16 (g==0) = out[m=p16][c=r]

            if (g == 0 && b < nBatch) {
                float* dst = out + (size_t)b * 48 + p16 * 3;
                dst[0] = D[0]; dst[1] = D[1]; dst[2] = D[2];
            }
        }
    }
}

extern "C" void kernel_launch(void* const* d_in, const int* in_sizes, int n_in,
                              void* d_out, int out_size, void* d_ws, size_t ws_size,
                              hipStream_t stream) {
    const float* prob = (const float*)d_in[0];
    const float* W1   = (const float*)d_in[1];
    const float* b1   = (const float*)d_in[2];
    const float* W2   = (const float*)d_in[3];
    const float* b2   = (const float*)d_in[4];
    float* out        = (float*)d_out;

    const int nBatch = in_sizes[0] / 48;                    // [B,16,3]
    const int totalWaves = GRID * (BLOCK / 64);
    const int bpw = (nBatch + totalWaves - 1) / totalWaves; // 8 at B=65536

    postpro_kernel<<<GRID, BLOCK, 0, stream>>>(prob, W1, b1, W2, b2, out, nBatch, bpw);
}

// Round 9
// 43.656 us; speedup vs baseline: 2.3539x; 1.0394x over previous
//
#include <hip/hip_runtime.h>
#include <cstdint>
#include <cstddef>

typedef __attribute__((ext_vector_type(4))) float f32x4;
typedef _Float16 h16x8 __attribute__((ext_vector_type(8)));

#define BLOCK 256
#define GRID  4096
#define NB    4

__device__ __forceinline__ uint32_t pk16(float a, float b) {
    // lo half = cvt(a), hi half = cvt(b), round-toward-zero
    return __builtin_bit_cast(uint32_t, __builtin_amdgcn_cvt_pkrtz(a, b));
}

// Lane l: p16 = l&15, g = l>>4. Element->feature convention for every MFMA
// operand: element j of chunk s <-> k = 32s + 8g + j (round-3/5-verified mirror).
__global__ __launch_bounds__(BLOCK, 4) void postpro_kernel(
    const float* __restrict__ prob,
    const float* __restrict__ W1,
    const float* __restrict__ b1,
    const float* __restrict__ W2,
    const float* __restrict__ b2,
    float* __restrict__ out,
    int nBatch, int bpw)
{
    __shared__ float sw[640];   // [0:512) W1 rows 0..3, [512:640) b1
    const int tid = threadIdx.x;
    for (int i = tid; i < 512; i += BLOCK) sw[i] = W1[i];
    for (int i = tid; i < 128; i += BLOCK) sw[512 + i] = b1[i];

    const int lane = tid & 63;
    const int p16  = lane & 15;
    const int g    = lane >> 4;
    const float fn = (float)p16;

    // W2 B-frags (fp16): element j of chunk s = W2[32s+8g+j][c=p16], 0 for c>=3
    h16x8 w2f[4];
    #pragma unroll
    for (int s = 0; s < 4; ++s) {
        union { h16x8 v; _Float16 h[8]; } pk;
        #pragma unroll
        for (int j = 0; j < 8; ++j) {
            const int k = 32 * s + 8 * g + j;
            pk.h[j] = (p16 < 3) ? (_Float16)W2[k * 3 + p16] : (_Float16)0.0f;
        }
        w2f[s] = pk.v;
    }
    const float binit = (p16 < 3) ? b2[p16] : 0.0f;   // b2 fold: sum(attn)=1
    const f32x4 yinit = {binit, binit, binit, binit};
    const f32x4 zero4 = {0.f, 0.f, 0.f, 0.f};

    const int wave = blockIdx.x * (BLOCK / 64) + (tid >> 6);
    const int b0   = wave * bpw;

    for (int bi = 0; bi < bpw; bi += NB) {
        const int bb = b0 + bi;

        // hoist all global prob loads (issued before the LDS sync)
        float p0[NB], p1[NB], p2[NB];
        #pragma unroll
        for (int u = 0; u < NB; ++u) {
            int b = bb + u; if (b > nBatch - 1) b = nBatch - 1;
            const float* pp = prob + (size_t)b * 48 + p16 * 3;
            p0[u] = pp[0]; p1[u] = pp[1]; p2[u] = pp[2];
        }

        if (bi == 0) __syncthreads();   // LDS ready

        f32x4 accS[NB], accY[NB];
        #pragma unroll
        for (int u = 0; u < NB; ++u) { accS[u] = zero4; accY[u] = yinit; }

        #pragma unroll
        for (int s = 0; s < 4; ++s) {
            const int h0 = 32 * s + 8 * g;
            const f32x4 r0a = *(const f32x4*)(sw + h0);
            const f32x4 r0b = *(const f32x4*)(sw + h0 + 4);
            const f32x4 r1a = *(const f32x4*)(sw + 128 + h0);
            const f32x4 r1b = *(const f32x4*)(sw + 128 + h0 + 4);
            const f32x4 r2a = *(const f32x4*)(sw + 256 + h0);
            const f32x4 r2b = *(const f32x4*)(sw + 256 + h0 + 4);
            const f32x4 w3a = *(const f32x4*)(sw + 384 + h0);
            const f32x4 w3b = *(const f32x4*)(sw + 384 + h0 + 4);
            const f32x4 b1a = *(const f32x4*)(sw + 512 + h0);
            const f32x4 b1b = *(const f32x4*)(sw + 512 + h0 + 4);

            float r0_[8], r1_[8], r2_[8], base_[8];
            #pragma unroll
            for (int j = 0; j < 4; ++j) {
                r0_[j] = r0a[j]; r0_[4 + j] = r0b[j];
                r1_[j] = r1a[j]; r1_[4 + j] = r1b[j];
                r2_[j] = r2a[j]; r2_[4 + j] = r2b[j];
                base_[j]     = fmaf(fn, w3a[j], b1a[j]);   // batch-invariant
                base_[4 + j] = fmaf(fn, w3b[j], b1b[j]);
            }

            #pragma unroll
            for (int u = 0; u < NB; ++u) {
                float H[8];
                #pragma unroll
                for (int j = 0; j < 8; ++j) {
                    float h = fmaf(p0[u], r0_[j], base_[j]);
                    h = fmaf(p1[u], r1_[j], h);
                    h = fmaf(p2[u], r2_[j], h);
                    H[j] = fmaxf(h, 0.0f);
                }
                union { h16x8 v; uint32_t q[4]; } Hf;
                #pragma unroll
                for (int t = 0; t < 4; ++t) Hf.q[t] = pk16(H[2 * t], H[2 * t + 1]);

                accS[u] = __builtin_amdgcn_mfma_f32_16x16x32_f16(Hf.v, Hf.v,   accS[u], 0, 0, 0);
                accY[u] = __builtin_amdgcn_mfma_f32_16x16x32_f16(Hf.v, w2f[s], accY[u], 0, 0, 0);
            }
        }

        #pragma unroll
        for (int u = 0; u < NB; ++u) {
            const int b = bb + u;
            // transposed softmax: accS[u][r] = S[4g+r][p16] = S[p16][4g+r] (symmetric)
            float m0 = fmaxf(fmaxf(accS[u][0], accS[u][1]), fmaxf(accS[u][2], accS[u][3]));
            m0 = fmaxf(m0, __shfl_xor(m0, 16));
            m0 = fmaxf(m0, __shfl_xor(m0, 32));
            const float e0 = __expf(accS[u][0] - m0);
            const float e1 = __expf(accS[u][1] - m0);
            const float e2 = __expf(accS[u][2] - m0);
            const float e3 = __expf(accS[u][3] - m0);
            float sm = (e0 + e1) + (e2 + e3);
            sm += __shfl_xor(sm, 16);
            sm += __shfl_xor(sm, 32);
            const float inv = __builtin_amdgcn_rcpf(sm);

            // epilogue: D[c][m] = sum_k Y'^T[c][k] attn^T[k][m], K=16 logical.
            union { h16x8 v; uint32_t q[4]; } Afr, Bfr;
            Afr.q[0] = pk16(accY[u][0], accY[u][1]);
            Afr.q[1] = pk16(accY[u][2], accY[u][3]);
            Afr.q[2] = 0u; Afr.q[3] = 0u;
            Bfr.q[0] = pk16(e0 * inv, e1 * inv);
            Bfr.q[1] = pk16(e2 * inv, e3 * inv);
            Bfr.q[2] = 0u; Bfr.q[3] = 0u;

            const f32x4 D = __builtin_amdgcn_mfma_f32_16x16x32_f16(Afr.v, Bfr.v, zero4, 0, 0, 0);
            // D reg r, lane p16 (g==0) = out[m=p16][c=r]

            if (g == 0 && b < nBatch) {
                float* dst = out + (size_t)b * 48 + p16 * 3;
                dst[0] = D[0]; dst[1] = D[1]; dst[2] = D[2];
            }
        }
    }
}

extern "C" void kernel_launch(void* const* d_in, const int* in_sizes, int n_in,
                              void* d_out, int out_size, void* d_ws, size_t ws_size,
                              hipStream_t stream) {
    const float* prob = (const float*)d_in[0];
    const float* W1   = (const float*)d_in[1];
    const float* b1   = (const float*)d_in[2];
    const float* W2   = (const float*)d_in[3];
    const float* b2   = (const float*)d_in[4];
    float* out        = (float*)d_out;

    const int nBatch = in_sizes[0] / 48;                    // [B,16,3]
    const int totalWaves = GRID * (BLOCK / 64);
    const int bpw = (nBatch + totalWaves - 1) / totalWaves; // 4 at B=65536

    postpro_kernel<<<GRID, BLOCK, 0, stream>>>(prob, W1, b1, W2, b2, out, nBatch, bpw);
}